// Round 6
// baseline (211.635 us; speedup 1.0000x reference)
//
#include <hip/hip_runtime.h>
#include <hip/hip_bf16.h>

// Problem constants: N=1024, C=32, T=8, V=64, K=3, CT=256
// out[n][c][v][t] = sum_k sum_j W[k][c*8+t][j] * U_k[j][v] + bias2T[c*8+t][v]
// U_k[j][v] = sum_u x[n][j][u] * A[k][u][v]
//
// R11: fit 4 waves/SIMD for real. Occupancy model fitting R5-R10:
// waves/SIMD = quantized 512/(VGPR + accumulator-AGPR); R5/R8/R10 were
// ~184 total (120 reported + 64 acc2) -> hard 2 waves/SIMD regardless of
// LDS headroom; every pipe 13-24% busy, sum ~= wall -> pipes serialize
// for lack of concurrent waves. This round cuts LIVENESS to <=128 total
// (the 4-waves/SIMD quantum) while keeping everything R7 punished:
// 16-thick stage2 MFMA runs, 4-wave blocks, grid 1024, single 33.8KB Ut,
// raw lgkm-only barriers.
//   (1) xf re-materialized from global per stage1 (-32 permanent regs;
//       x_n is L2/L3-hot after first read, +64 cvt_pk/wave only)
//   (2) stage1 mt-split: acc1[4nt]=16 regs per slice, written immediately
//       (stage1 acc peak 64+16, not 64+64); Asw re-reads are L1-resident
//   (3) aw single-buffered (-16): no depth-2 rotate / cross-k refill;
//       the 4th wave/SIMD covers the exposed L2 latency
// __launch_bounds__(256,4): budget 128, ABOVE the ~110-120 liveness
// (R6's spill was cap 128 under liveness 184 - different situation).
// Spill canary: WRITE_SIZE must stay exactly 65536 KB.
// R7 lesson: never thin stage2's per-ks MFMA run. R8/R10 lesson:
// residency budget and source-level prefetch are both already-saturated
// levers; only true wave concurrency remains.

typedef __attribute__((ext_vector_type(8))) short bf16x8;
typedef __attribute__((ext_vector_type(4))) float f32x4;

#define RAWBAR() asm volatile("s_waitcnt lgkmcnt(0)\n\ts_barrier" ::: "memory")

__device__ __forceinline__ short f2bf(float f) {
  union { float f; unsigned u; } c; c.f = f;
  unsigned r = c.u + 0x7FFFu + ((c.u >> 16) & 1u);   // RNE
  return (short)(r >> 16);
}

__device__ __forceinline__ unsigned pkbf(float a, float b) {
  float2 t; t.x = a; t.y = b;
  union { __hip_bfloat162 h; unsigned u; } c;
  c.h = __float22bfloat162_rn(t);   // v_cvt_pk_bf16_f32, RNE
  return c.u;
}

// ---------------- workspace layout (bytes) ----------------
// Wsw   : short[196608] @ 0        fragment-ordered W  (k,wv4,mt4,ks8,lane,e)
// Asw   : short[12288]  @ 393216   fragment-ordered A^T (k,ks,nt,lane,e)
// biasCM: float[16384]  @ 417792   column-major bias: biasCM[w*256 + d]
#define ASW_OFF  393216
#define BIAS_OFF 417792

__global__ __launch_bounds__(256) void prep_kernel(
    const float* __restrict__ W, const float* __restrict__ b,
    const float* __restrict__ A, short* __restrict__ Wsw,
    short* __restrict__ Asw, float* __restrict__ biasCM) {
  int t = blockIdx.x * 256 + threadIdx.x;
  if (t < 196608) {
    // Wsw flat = ((((k*4+wv)*4+mt)*8+ks)*64 + lane)*8 + e
    int e = t & 7, l = (t >> 3) & 63, ks = (t >> 9) & 7, mt = (t >> 12) & 3,
        wv = (t >> 14) & 3, k = t >> 16;
    int d = 64 * wv + 16 * mt + (l & 15);
    int c = 32 * ks + 8 * (l >> 4) + e;
    Wsw[t] = f2bf(W[(k * 256 + d) * 256 + c]);
  } else if (t < 196608 + 12288) {
    // Asw flat = (((k*2+ks)*4+nt)*64 + lane)*8 + e ; value = A[k][v][w]
    int t2 = t - 196608;
    int e = t2 & 7, l = (t2 >> 3) & 63, nt = (t2 >> 9) & 3, ks = (t2 >> 11) & 1,
        k = t2 >> 12;
    int w = nt * 16 + (l & 15);
    int v = ks * 32 + (l >> 4) * 8 + e;
    Asw[t2] = f2bf(A[(k * 64 + v) * 64 + w]);
  } else {
    // biasCM[w*256 + d] = sum_k (sum_v A[k][v][w]) * b[k][d]
    int t2 = t - 196608 - 12288;
    int w = t2 >> 8, d = t2 & 255;
    float s = 0.f;
    for (int k = 0; k < 3; ++k) {
      float cs = 0.f;
#pragma unroll
      for (int v = 0; v < 64; ++v) cs += A[(k * 64 + v) * 64 + w];
      s += cs * b[k * 256 + d];
    }
    biasCM[t2] = s;
  }
}

#define UT_STRIDE 264  // bf16 elems per Ut row (256 + 8 pad), 528B rows

// stage-1: compute U_k rows [64wv, 64wv+64) and write transposed into Ut.
// mt-split: one 16-row slice at a time -> acc1 is only 16 regs, x fragments
// re-materialized per slice (x is L2-hot), Asw re-read per slice (L1-hot).
__device__ __forceinline__ void stage1(
    const float* __restrict__ xn, const short* __restrict__ Asw, int k,
    short* __restrict__ Utw, int wv, int lane, int li, int lq) {
  const short* AswK = Asw + k * 4096;
#pragma unroll
  for (int mt = 0; mt < 4; ++mt) {
    // x rows 64wv+16mt+li, cols 32ks+8lq..+7 -> 2 bf16x8 fragments
    bf16x8 xk[2];
#pragma unroll
    for (int ks = 0; ks < 2; ++ks) {
      const float4* p =
          (const float4*)(xn + (64 * wv + 16 * mt + li) * 64 + 32 * ks + 8 * lq);
      float4 f0 = p[0], f1 = p[1];
      union { bf16x8 v; unsigned u[4]; } t;
      t.u[0] = pkbf(f0.x, f0.y); t.u[1] = pkbf(f0.z, f0.w);
      t.u[2] = pkbf(f1.x, f1.y); t.u[3] = pkbf(f1.z, f1.w);
      xk[ks] = t.v;
    }

    f32x4 acc1[4];
#pragma unroll
    for (int nt = 0; nt < 4; ++nt) acc1[nt] = (f32x4){0.f, 0.f, 0.f, 0.f};

#pragma unroll
    for (int ks = 0; ks < 2; ++ks)
#pragma unroll
      for (int nt = 0; nt < 4; ++nt) {
        bf16x8 bfr = *(const bf16x8*)(AswK + ((ks * 4 + nt) * 64 + lane) * 8);
        acc1[nt] = __builtin_amdgcn_mfma_f32_16x16x32_bf16(
            xk[ks], bfr, acc1[nt], 0, 0, 0);
      }

#pragma unroll
    for (int nt = 0; nt < 4; ++nt) {
      int w = nt * 16 + li;
      int ct = 64 * wv + 16 * mt + 4 * lq;
      union { unsigned u[2]; unsigned long long ull; } p;
      p.u[0] = pkbf(acc1[nt][0], acc1[nt][1]);
      p.u[1] = pkbf(acc1[nt][2], acc1[nt][3]);
      *(unsigned long long*)(&Utw[w * UT_STRIDE + ct]) = p.ull;
    }
  }
}

__global__ __launch_bounds__(256, 4) void gcn_main(
    const float* __restrict__ x, const short* __restrict__ Wsw,
    const short* __restrict__ Asw, const float* __restrict__ biasCM,
    float* __restrict__ out) {
  __shared__ short Ut[64 * UT_STRIDE];  // 33792 B; 4 blocks/CU by LDS

  const int tid = threadIdx.x;
  const int wv = tid >> 6;        // wave 0..3, owns d-rows [64wv, 64wv+64)
  const int lane = tid & 63;
  const int li = lane & 15;
  const int lq = lane >> 4;
  const int n = blockIdx.x;

  const float* xn = x + (size_t)n * 16384;
  float* outn = out + (size_t)n * 16384;

  // ---- acc2 init = bias (epilogue becomes a pure store); biasCM is L2-hot
  f32x4 acc2[4][4];
#pragma unroll
  for (int mt = 0; mt < 4; ++mt)
#pragma unroll
    for (int nt = 0; nt < 4; ++nt) {
      const float4 bb = *(const float4*)(biasCM + (nt * 16 + li) * 256 +
                                         64 * wv + 16 * mt + 4 * lq);
      acc2[mt][nt] = (f32x4){bb.x, bb.y, bb.z, bb.w};
    }

  // ---- preamble: U_0 -> Ut
  stage1(xn, Asw, 0, Ut, wv, lane, li, lq);
  RAWBAR();  // Ut(k=0) visible

#pragma unroll
  for (int k = 0; k < 3; ++k) {
    const short* WswK = Wsw + (k * 4 + wv) * 16384;

    // ---------- stage 2: acc2 += W_k[rows 64wv..] @ U_k (from Ut) ----------
    // aw single-buffered: loads at step top; compiler pipelines within the
    // 128-reg budget, 4 waves/SIMD cover the remainder.
#pragma unroll
    for (int ks = 0; ks < 8; ++ks) {
      bf16x8 aw[4], bu[4];
#pragma unroll
      for (int mt = 0; mt < 4; ++mt)
        aw[mt] = *(const bf16x8*)(WswK + ((mt * 8 + ks) * 64 + lane) * 8);
#pragma unroll
      for (int nt = 0; nt < 4; ++nt)
        bu[nt] = *(const bf16x8*)(&Ut[(nt * 16 + li) * UT_STRIDE + 32 * ks + 8 * lq]);

#pragma unroll
      for (int mt = 0; mt < 4; ++mt)
#pragma unroll
        for (int nt = 0; nt < 4; ++nt)
          acc2[mt][nt] = __builtin_amdgcn_mfma_f32_16x16x32_bf16(
              aw[mt], bu[nt], acc2[mt][nt], 0, 0, 0);
    }

    // ---------- single-buffer handoff: WAR barrier, write U_{k+1}, RAW
    // barrier. lgkm-only: every wave's LDS ops complete before it enters
    // the barrier, so reads(k) finish before writes(k+1) start.
    if (k < 2) {
      RAWBAR();                              // stage2(k) reads done (WAR)
      stage1(xn, Asw, k + 1, Ut, wv, lane, li, lq);
      RAWBAR();                              // Ut(k+1) visible (RAW)
    }
  }

  // ---------- epilogue: direct float4 stores from C-layout ----------
  // d = 64wv+16mt+4lq+r -> c = 8wv+2mt+(lq>>1), t = 4(lq&1)+r, w = 16nt+li
#pragma unroll
  for (int mt = 0; mt < 4; ++mt)
#pragma unroll
    for (int nt = 0; nt < 4; ++nt) {
      float4 vv;
      vv.x = acc2[mt][nt][0];
      vv.y = acc2[mt][nt][1];
      vv.z = acc2[mt][nt][2];
      vv.w = acc2[mt][nt][3];
      *(float4*)(outn + (8 * wv + 2 * mt + (lq >> 1)) * 512 +
                 (nt * 16 + li) * 8 + 4 * (lq & 1)) = vv;
    }
}

extern "C" void kernel_launch(void* const* d_in, const int* in_sizes, int n_in,
                              void* d_out, int out_size, void* d_ws, size_t ws_size,
                              hipStream_t stream) {
  (void)in_sizes; (void)n_in; (void)out_size; (void)ws_size;
  const float* x = (const float*)d_in[0];
  const float* W = (const float*)d_in[1];
  const float* b = (const float*)d_in[2];
  const float* A = (const float*)d_in[3];
  float* out = (float*)d_out;

  short* Wsw = (short*)d_ws;
  short* Asw = (short*)((char*)d_ws + ASW_OFF);
  float* biasCM = (float*)((char*)d_ws + BIAS_OFF);

  // prep: 196608 (W) + 12288 (A) + 16384 (bias) = 225280 threads = 880 blocks
  prep_kernel<<<880, 256, 0, stream>>>(W, b, A, Wsw, Asw, biasCM);
  gcn_main<<<1024, 256, 0, stream>>>(x, Wsw, Asw, biasCM, out);
}

// Round 7
// 182.658 us; speedup vs baseline: 1.1586x; 1.1586x over previous
//
#include <hip/hip_runtime.h>
#include <hip/hip_bf16.h>

// Problem constants: N=1024, C=32, T=8, V=64, K=3, CT=256
// out[n][c][v][t] = sum_k sum_j W[k][c*8+t][j] * U_k[j][v] + bias2T[c*8+t][v]
// U_k[j][v] = sum_u x[n][j][u] * A[k][u][v]
//
// R12: 2-n fusion. Each block computes n1=bid AND n2=bid+512 in the same
// pass: stage2 loads each aw fragment ONCE and feeds two 16-MFMA runs
// (acc2a for n1, acc2b for n2). Why: R5-R11 established (a) 2 waves/SIMD
// is a hard ceiling (64-AGPR accumulator + staging can't fit the 128-reg
// tier; every occupancy attempt spilled or thinned - R6/R7/R9/R11); (b)
// at 2 waves/SIMD the wall is issue+latency dominated, with the aw global
// stream the largest VMEM consumer and grid 1024 = 2 sequential block
// generations. Fusion halves the W stream per unit work (chip L2 W
// traffic 393->197MB), gives each aw load 32 MFMAs of cover (>200cy L2
// latency -> single-buffered aw is enough, rotate dropped), halves
// barriers per n, and makes grid 512 = exactly 2 blocks/CU x 256 CU =
// ONE generation (no inter-generation serialization).
// Unified-file register plan (R11 lesson: VGPR budget includes AGPRs):
// stage2 peak ~208 (128 acc + 32 aw + 32 bu + addr), stage1 peak ~248
// (128 acc + 64 acc1 + 32 xf + 8 bfr); (256,2) cap=256 > liveness.
// xf re-materialized per stage1 (x is L2/L3-hot after first touch);
// sched_barrier(0) between the two stage1 calls pins call order so the
// scheduler can't co-pipeline them and blow the register peak.
// Spill canary: WRITE_SIZE must stay exactly 65536 KB (R6/R9/R11).
// R7 lesson kept: stage2 MFMA runs stay 16-thick per acc (now 32 per aw).
// Raw lgkm-only barriers: cross-wave comm is LDS-only; global loads are
// wave-private and legally stay outstanding across s_barrier.

typedef __attribute__((ext_vector_type(8))) short bf16x8;
typedef __attribute__((ext_vector_type(4))) float f32x4;

#define RAWBAR() asm volatile("s_waitcnt lgkmcnt(0)\n\ts_barrier" ::: "memory")

__device__ __forceinline__ short f2bf(float f) {
  union { float f; unsigned u; } c; c.f = f;
  unsigned r = c.u + 0x7FFFu + ((c.u >> 16) & 1u);   // RNE
  return (short)(r >> 16);
}

__device__ __forceinline__ unsigned pkbf(float a, float b) {
  float2 t; t.x = a; t.y = b;
  union { __hip_bfloat162 h; unsigned u; } c;
  c.h = __float22bfloat162_rn(t);   // v_cvt_pk_bf16_f32, RNE
  return c.u;
}

// ---------------- workspace layout (bytes) ----------------
// Wsw   : short[196608] @ 0        fragment-ordered W  (k,wv4,mt4,ks8,lane,e)
// Asw   : short[12288]  @ 393216   fragment-ordered A^T (k,ks,nt,lane,e)
// biasCM: float[16384]  @ 417792   column-major bias: biasCM[w*256 + d]
#define ASW_OFF  393216
#define BIAS_OFF 417792

__global__ __launch_bounds__(256) void prep_kernel(
    const float* __restrict__ W, const float* __restrict__ b,
    const float* __restrict__ A, short* __restrict__ Wsw,
    short* __restrict__ Asw, float* __restrict__ biasCM) {
  int t = blockIdx.x * 256 + threadIdx.x;
  if (t < 196608) {
    // Wsw flat = ((((k*4+wv)*4+mt)*8+ks)*64 + lane)*8 + e
    int e = t & 7, l = (t >> 3) & 63, ks = (t >> 9) & 7, mt = (t >> 12) & 3,
        wv = (t >> 14) & 3, k = t >> 16;
    int d = 64 * wv + 16 * mt + (l & 15);
    int c = 32 * ks + 8 * (l >> 4) + e;
    Wsw[t] = f2bf(W[(k * 256 + d) * 256 + c]);
  } else if (t < 196608 + 12288) {
    // Asw flat = (((k*2+ks)*4+nt)*64 + lane)*8 + e ; value = A[k][v][w]
    int t2 = t - 196608;
    int e = t2 & 7, l = (t2 >> 3) & 63, nt = (t2 >> 9) & 3, ks = (t2 >> 11) & 1,
        k = t2 >> 12;
    int w = nt * 16 + (l & 15);
    int v = ks * 32 + (l >> 4) * 8 + e;
    Asw[t2] = f2bf(A[(k * 64 + v) * 64 + w]);
  } else {
    // biasCM[w*256 + d] = sum_k (sum_v A[k][v][w]) * b[k][d]
    int t2 = t - 196608 - 12288;
    int w = t2 >> 8, d = t2 & 255;
    float s = 0.f;
    for (int k = 0; k < 3; ++k) {
      float cs = 0.f;
#pragma unroll
      for (int v = 0; v < 64; ++v) cs += A[(k * 64 + v) * 64 + w];
      s += cs * b[k * 256 + d];
    }
    biasCM[t2] = s;
  }
}

#define UT_STRIDE 264  // bf16 elems per Ut row (256 + 8 pad), 528B rows

// stage-1: compute U_k rows [64wv, 64wv+64) of one n, write transposed
// into Ut. xf loaded internally (re-materialized; x is L2/L3-hot after
// the k=0 touch) so no permanent 32-reg xf across the whole kernel.
__device__ __forceinline__ void stage1(
    const float* __restrict__ xn, const short* __restrict__ Asw, int k,
    short* __restrict__ Utw, int wv, int lane, int li, int lq) {
  const short* AswK = Asw + k * 4096;

  bf16x8 xf[2][4];
#pragma unroll
  for (int ks = 0; ks < 2; ++ks)
#pragma unroll
    for (int mt = 0; mt < 4; ++mt) {
      const float4* p =
          (const float4*)(xn + (64 * wv + 16 * mt + li) * 64 + 32 * ks + 8 * lq);
      float4 f0 = p[0], f1 = p[1];
      union { bf16x8 v; unsigned u[4]; } t;
      t.u[0] = pkbf(f0.x, f0.y); t.u[1] = pkbf(f0.z, f0.w);
      t.u[2] = pkbf(f1.x, f1.y); t.u[3] = pkbf(f1.z, f1.w);
      xf[ks][mt] = t.v;
    }

  f32x4 acc1[4][4];
#pragma unroll
  for (int mt = 0; mt < 4; ++mt)
#pragma unroll
    for (int nt = 0; nt < 4; ++nt)
      acc1[mt][nt] = (f32x4){0.f, 0.f, 0.f, 0.f};

#pragma unroll
  for (int ks = 0; ks < 2; ++ks) {
    bf16x8 bfr[4];
#pragma unroll
    for (int nt = 0; nt < 4; ++nt)
      bfr[nt] = *(const bf16x8*)(AswK + ((ks * 4 + nt) * 64 + lane) * 8);
#pragma unroll
    for (int mt = 0; mt < 4; ++mt)
#pragma unroll
      for (int nt = 0; nt < 4; ++nt)
        acc1[mt][nt] = __builtin_amdgcn_mfma_f32_16x16x32_bf16(
            xf[ks][mt], bfr[nt], acc1[mt][nt], 0, 0, 0);
  }

#pragma unroll
  for (int mt = 0; mt < 4; ++mt)
#pragma unroll
    for (int nt = 0; nt < 4; ++nt) {
      int w = nt * 16 + li;
      int ct = 64 * wv + 16 * mt + 4 * lq;
      union { unsigned u[2]; unsigned long long ull; } p;
      p.u[0] = pkbf(acc1[mt][nt][0], acc1[mt][nt][1]);
      p.u[1] = pkbf(acc1[mt][nt][2], acc1[mt][nt][3]);
      *(unsigned long long*)(&Utw[w * UT_STRIDE + ct]) = p.ull;
    }
}

// d = 64wv+16mt+4lq+r -> c = 8wv+2mt+(lq>>1), t = 4(lq&1)+r, w = 16nt+li
__device__ __forceinline__ void store_out(float* __restrict__ outn,
                                          const f32x4 (&acc2)[4][4], int wv,
                                          int li, int lq) {
#pragma unroll
  for (int mt = 0; mt < 4; ++mt)
#pragma unroll
    for (int nt = 0; nt < 4; ++nt) {
      float4 vv;
      vv.x = acc2[mt][nt][0];
      vv.y = acc2[mt][nt][1];
      vv.z = acc2[mt][nt][2];
      vv.w = acc2[mt][nt][3];
      *(float4*)(outn + (8 * wv + 2 * mt + (lq >> 1)) * 512 +
                 (nt * 16 + li) * 8 + 4 * (lq & 1)) = vv;
    }
}

__global__ __launch_bounds__(256, 2) void gcn_main(
    const float* __restrict__ x, const short* __restrict__ Wsw,
    const short* __restrict__ Asw, const float* __restrict__ biasCM,
    float* __restrict__ out) {
  __shared__ short Ut1[64 * UT_STRIDE];  // 33792 B each; 67584 total
  __shared__ short Ut2[64 * UT_STRIDE];

  const int tid = threadIdx.x;
  const int wv = tid >> 6;        // wave 0..3, owns d-rows [64wv, 64wv+64)
  const int lane = tid & 63;
  const int li = lane & 15;
  const int lq = lane >> 4;

  const int n1 = blockIdx.x;          // grid 512: one generation chip-wide
  const int n2 = blockIdx.x + 512;

  const float* x1 = x + (size_t)n1 * 16384;
  const float* x2 = x + (size_t)n2 * 16384;

  // ---- acc init = bias (same for both n; loaded once, copied)
  f32x4 acc2a[4][4], acc2b[4][4];
#pragma unroll
  for (int mt = 0; mt < 4; ++mt)
#pragma unroll
    for (int nt = 0; nt < 4; ++nt) {
      const float4 bb = *(const float4*)(biasCM + (nt * 16 + li) * 256 +
                                         64 * wv + 16 * mt + 4 * lq);
      acc2a[mt][nt] = (f32x4){bb.x, bb.y, bb.z, bb.w};
      acc2b[mt][nt] = acc2a[mt][nt];
    }

  // ---- preamble: U_0(n1) -> Ut1, U_0(n2) -> Ut2
  stage1(x1, Asw, 0, Ut1, wv, lane, li, lq);
  __builtin_amdgcn_sched_barrier(0);   // pin order: cap register peak
  stage1(x2, Asw, 0, Ut2, wv, lane, li, lq);
  RAWBAR();  // both Ut visible; nothing else drained

#pragma unroll
  for (int k = 0; k < 3; ++k) {
    const short* WswK = Wsw + (k * 4 + wv) * 16384;

    // ---------- stage 2: one aw load feeds BOTH n's 16-MFMA runs ----------
#pragma unroll
    for (int ks = 0; ks < 8; ++ks) {
      bf16x8 aw[4];
#pragma unroll
      for (int mt = 0; mt < 4; ++mt)
        aw[mt] = *(const bf16x8*)(WswK + ((mt * 8 + ks) * 64 + lane) * 8);

      bf16x8 bu[4];
#pragma unroll
      for (int nt = 0; nt < 4; ++nt)
        bu[nt] = *(const bf16x8*)(&Ut1[(nt * 16 + li) * UT_STRIDE + 32 * ks + 8 * lq]);
#pragma unroll
      for (int mt = 0; mt < 4; ++mt)
#pragma unroll
        for (int nt = 0; nt < 4; ++nt)
          acc2a[mt][nt] = __builtin_amdgcn_mfma_f32_16x16x32_bf16(
              aw[mt], bu[nt], acc2a[mt][nt], 0, 0, 0);

#pragma unroll
      for (int nt = 0; nt < 4; ++nt)
        bu[nt] = *(const bf16x8*)(&Ut2[(nt * 16 + li) * UT_STRIDE + 32 * ks + 8 * lq]);
#pragma unroll
      for (int mt = 0; mt < 4; ++mt)
#pragma unroll
        for (int nt = 0; nt < 4; ++nt)
          acc2b[mt][nt] = __builtin_amdgcn_mfma_f32_16x16x32_bf16(
              aw[mt], bu[nt], acc2b[mt][nt], 0, 0, 0);
    }

    // ---------- handoff: WAR barrier, write U_{k+1} for both n, RAW barrier
    if (k < 2) {
      RAWBAR();                            // stage2(k) Ut reads done (WAR)
      stage1(x1, Asw, k + 1, Ut1, wv, lane, li, lq);
      __builtin_amdgcn_sched_barrier(0);   // pin order: cap register peak
      stage1(x2, Asw, k + 1, Ut2, wv, lane, li, lq);
      RAWBAR();                            // Ut(k+1) visible (RAW)
    }
  }

  // ---------- epilogue ----------
  store_out(out + (size_t)n1 * 16384, acc2a, wv, li, lq);
  store_out(out + (size_t)n2 * 16384, acc2b, wv, li, lq);
}

extern "C" void kernel_launch(void* const* d_in, const int* in_sizes, int n_in,
                              void* d_out, int out_size, void* d_ws, size_t ws_size,
                              hipStream_t stream) {
  (void)in_sizes; (void)n_in; (void)out_size; (void)ws_size;
  const float* x = (const float*)d_in[0];
  const float* W = (const float*)d_in[1];
  const float* b = (const float*)d_in[2];
  const float* A = (const float*)d_in[3];
  float* out = (float*)d_out;

  short* Wsw = (short*)d_ws;
  short* Asw = (short*)((char*)d_ws + ASW_OFF);
  float* biasCM = (float*)((char*)d_ws + BIAS_OFF);

  // prep: 196608 (W) + 12288 (A) + 16384 (bias) = 225280 threads = 880 blocks
  prep_kernel<<<880, 256, 0, stream>>>(W, b, A, Wsw, Asw, biasCM);
  // 512 blocks = 2 blocks/CU x 256 CU exactly: one generation; each block
  // computes n and n+512 sharing one W stream
  gcn_main<<<512, 256, 0, stream>>>(x, Wsw, Asw, biasCM, out);
}